// Round 19
// baseline (140.893 us; speedup 1.0000x reference)
//
#include <hip/hip_runtime.h>
#include <hip/hip_fp16.h>

// SSIM loss, fused separable 11x11 Gaussian conv + SSIM map + mean.
// Images: 32 x 1 x 512 x 512 fp32. Output: 1 fp32 scalar.
//
// R19 = R18 + fused last-block reduction (kills the 2nd kernel launch).
// Each block: partial[wgid] = sum; __threadfence(); ticket=atomicAdd(cnt).
// Ticket 4095's block acquire-fences and reduces all 4096 partials in
// FIXED index order -> deterministic. Counter zeroed per launch by a
// captured hipMemsetAsync node.
//
// R18 structure (unchanged): wave-role specialization
//   DMA r1: all threads chunk=tid. r2: waves 0-4 ch=512+tid (pad-safe).
//   per-wave counted waits: w0-4 vmcnt(2), w5-7 vmcnt(0); no barrier
//   before prepass-low. Phase A: w5-7 stage2-low || w0-4 prepass-high.
//   Phase B: w5-7 stage2-high || w0-4 stage3 rows 0..35. Phase C: all
//   stage3 rows 36..63. Packed-fp16 conv + pk epilogue (1/8 scale fold),
//   async global_load_lds, prepass pack + LDS aliasing, XCD swizzle.
//
// Alias map (HSTR=36, NPIXA=3328 incl pad): h rows 0..45 = dwords<1656 =
// chunks<414 (dead after prepass-low). h rows 46..73 = dwords 1656..2663
// (dead after prepass-high). prepass-high touches dwords 2048+ only.
// PAD dwords 3256..3327 never aliased.

#define IMGW 512
#define IMGH 512
#define NIMG 32
#define TW 32
#define TH 64
#define IN_H 74        // TH + 10
#define IN_W 44        // sPK row stride (dwords); cols 0..41 used
#define HSTR 36        // h row stride (dwords)
#define NPIX (IN_H * IN_W)     // 3256
#define NPIXA 3328     // raw region incl 18-chunk DMA overflow pad
#define NCHUNK (IN_H * 11)     // 814 16B chunks per image tile
#define NBX 16
#define NBY 8
#define NBLOCKS (NBX * NBY * NIMG)   // 4096
#define NT 512

typedef __attribute__((address_space(1))) const uint32_t ga_u32;
typedef __attribute__((address_space(3))) uint32_t ls_u32;

__device__ __forceinline__ void load16_lds(const float* g, float* l) {
  __builtin_amdgcn_global_load_lds((ga_u32*)g, (ls_u32*)l, 16, 0, 0);
}
__device__ __forceinline__ __half2 h2_of(uint32_t w) {
  return __builtin_bit_cast(__half2, w);
}
__device__ __forceinline__ uint32_t u_of(__half2 h) {
  return __builtin_bit_cast(uint32_t, h);
}
__device__ __forceinline__ void lds_barrier() {
  asm volatile("s_waitcnt lgkmcnt(0)" ::: "memory");
  __builtin_amdgcn_s_barrier();
  __builtin_amdgcn_sched_barrier(0);
}

__global__ __launch_bounds__(NT, 8) void ssim_main(
    const float* __restrict__ img1, const float* __restrict__ img2,
    float* __restrict__ partial, unsigned int* __restrict__ counter,
    float* __restrict__ out) {
  __shared__ uint32_t uRaw[NPIXA * 2];  // raw A | raw B (each w/ pad)
  __shared__ uint32_t sPK[NPIX];        // packed (a,b) half2
  __shared__ float sWave[8];
  __shared__ int sLast;
  float* sA = (float*)uRaw;
  float* sB = (float*)(uRaw + NPIXA);
  uint32_t* hAB = uRaw;                 // [74][HSTR] aliases raw-A
  uint32_t* hPM = uRaw + NPIXA;         // [74][HSTR] aliases raw-B

  // Unnormalized Gaussian, 2*sigma^2 = 4 (faithful to reference).
  constexpr float g[11] = {0.0019304541f, 0.018315639f, 0.10539922f,
                           0.36787944f,   0.7788008f,   1.0f,
                           0.7788008f,    0.36787944f,  0.10539922f,
                           0.018315639f,  0.0019304541f};

  __half2 gh[11], gh8[11];
#pragma unroll
  for (int k = 0; k < 11; ++k) {
    gh[k] = __float2half2_rn(g[k]);
    gh8[k] = __float2half2_rn(g[k] * 0.125f);   // stage-3 scale fold
  }
  const __half2 c1m1 = __floats2half2_rn(1.0f, -1.0f);
  const __half2 kQS = __float2half2_rn(0.0625f);
  const __half2 kQD = __float2half2_rn(0.03125f);
  const __half2 C1s = __float2half2_rn(6.5025f / 64.0f);
  const __half2 C2s = __float2half2_rn(58.5225f / 64.0f);
  const __half2 htwo = __float2half2_rn(2.0f);

  const int tid = threadIdx.x;
  const int wid = tid >> 6;
  // XCD-chunked swizzle: each of 8 XCDs gets 512 consecutive tiles.
  const int bid = blockIdx.x;
  const int wgid = (bid & 7) * (NBLOCKS / 8) + (bid >> 3);
  const int img = wgid >> 7;
  const int by = (wgid >> 4) & 7;
  const int bx = wgid & 15;
  const int x0 = bx * TW - 5;
  const int y0 = by * TH - 5;
  const float* __restrict__ p1 = img1 + (size_t)img * (IMGW * IMGH);
  const float* __restrict__ p2 = img2 + (size_t)img * (IMGW * IMGH);
  const bool borderBlk =
      (bx == 0) || (bx == NBX - 1) || (by == 0) || (by == NBY - 1);

  auto src_of = [&](int ch) {
    int r = ch / 11;
    int cg = ch - r * 11;
    int gy = y0 + r;
    int gx = x0 + 4 * cg;
    int gyc = min(max(gy, 0), IMGH - 1);
    int gxc = min(max(gx, 0), IMGW - 4);
    return gyc * IMGW + gxc;
  };

  // ---- Stage 0: DMA. r1: all (own chunk). r2: waves 0-4 contiguous. ----
  {
    int src = src_of(tid);
    load16_lds(p1 + src, &sA[tid * 4]);
    load16_lds(p2 + src, &sB[tid * 4]);
  }
  if (wid < 5) {
    int ch = 512 + tid;                  // 512..831 (814+ -> pad dst)
    int src = src_of(min(ch, NCHUNK - 1));
    load16_lds(p1 + src, &sA[ch * 4]);
    load16_lds(p2 + src, &sB[ch * 4]);
    asm volatile("s_waitcnt vmcnt(2)" ::: "memory");  // r1 retired
  } else {
    asm volatile("s_waitcnt vmcnt(0)" ::: "memory");  // r1 retired
  }
  __builtin_amdgcn_sched_barrier(0);

  // ---- prepass worker: pack one chunk (a,b)->half2 into sPK ----
  auto prepass_chunk = [&](int ch) {
    float4 a = *(const float4*)&sA[ch * 4];
    float4 b = *(const float4*)&sB[ch * 4];
    uint4 w;
    if (!borderBlk) {
      w.x = u_of(__floats2half2_rn(a.x, b.x));
      w.y = u_of(__floats2half2_rn(a.y, b.y));
      w.z = u_of(__floats2half2_rn(a.z, b.z));
      w.w = u_of(__floats2half2_rn(a.w, b.w));
    } else {
      int r = ch / 11;
      int cg = ch - r * 11;
      int gy = y0 + r;
      int gx = x0 + 4 * cg;
      bool rowok = (gy >= 0) && (gy < IMGH);
      float av[4] = {a.x, a.y, a.z, a.w};
      float bv[4] = {b.x, b.y, b.z, b.w};
      uint32_t* wp = (uint32_t*)&w;
#pragma unroll
      for (int j = 0; j < 4; ++j) {
        bool ok = rowok && (gx + j >= 0) && (gx + j < IMGW);
        wp[j] = u_of(__floats2half2_rn(ok ? av[j] : 0.f, ok ? bv[j] : 0.f));
      }
    }
    *(uint4*)&sPK[ch * 4] = w;
  };

  // ---- stage2 worker: 8-wide tasks over thread range [tbase,tbase+tcnt) ----
  auto stage2 = [&](int rowbase, int nrows, int tbase, int tcnt) {
    for (int idx = tid - tbase; idx < nrows * 4; idx += tcnt) {
      int r = rowbase + (idx >> 2);
      int c0 = (idx & 3) << 3;
      int base = r * IN_W + c0;
      __half2 ab[18], pm2[18];
      {
        uint4 w0 = *(const uint4*)&sPK[base];
        uint4 w1 = *(const uint4*)&sPK[base + 4];
        uint4 w2 = *(const uint4*)&sPK[base + 8];
        uint4 w3 = *(const uint4*)&sPK[base + 12];
        uint2 w4 = *(const uint2*)&sPK[base + 16];
        uint32_t ws[18] = {w0.x, w0.y, w0.z, w0.w, w1.x, w1.y, w1.z, w1.w,
                           w2.x, w2.y, w2.z, w2.w, w3.x, w3.y, w3.z, w3.w,
                           w4.x, w4.y};
#pragma unroll
        for (int k = 0; k < 18; ++k) {
          __half2 w = h2_of(ws[k]);
          ab[k] = w;
          __half2 t = __hfma2(__lowhigh2highlow(w), c1m1, w);  // (p, -m)
          pm2[k] = __hmul2(t, t);                              // (p2, m2)
        }
      }
      uint32_t oab[8], opm[8];
#pragma unroll
      for (int o = 0; o < 8; ++o) {
        __half2 cab = __float2half2_rn(0.0f);
        __half2 cpm = __float2half2_rn(0.0f);
#pragma unroll
        for (int k = 0; k < 11; ++k) {
          cab = __hfma2(gh[k], ab[o + k], cab);
          cpm = __hfma2(gh[k], pm2[o + k], cpm);
        }
        oab[o] = u_of(cab);
        opm[o] = u_of(cpm);
      }
      int hb = r * HSTR + c0;
      *(uint4*)&hAB[hb] = make_uint4(oab[0], oab[1], oab[2], oab[3]);
      *(uint4*)&hAB[hb + 4] = make_uint4(oab[4], oab[5], oab[6], oab[7]);
      *(uint4*)&hPM[hb] = make_uint4(opm[0], opm[1], opm[2], opm[3]);
      *(uint4*)&hPM[hb + 4] = make_uint4(opm[4], opm[5], opm[6], opm[7]);
    }
  };

  float ssum = 0.f;
  // ---- stage3 worker: 2-row x 2-col groups, rows r0base..+2*ngroups ----
  auto stage3 = [&](int r0base, int ngroups, int tbase, int tcnt) {
    for (int t = tid - tbase; t < ngroups * 16; t += tcnt) {
      int cp = t & 15;
      int r0 = r0base + ((t >> 4) << 1);
      __half2 aAB0[2], aAB1[2], aPM0[2], aPM1[2];
#pragma unroll
      for (int o = 0; o < 2; ++o) {
        aAB0[o] = __float2half2_rn(0.f);
        aAB1[o] = __float2half2_rn(0.f);
        aPM0[o] = __float2half2_rn(0.f);
        aPM1[o] = __float2half2_rn(0.f);
      }
#pragma unroll
      for (int k = 0; k < 12; ++k) {
        int row = r0 + k;
        uint2 ab = *(const uint2*)&hAB[row * HSTR + 2 * cp];
        uint2 pm = *(const uint2*)&hPM[row * HSTR + 2 * cp];
#pragma unroll
        for (int o = 0; o < 2; ++o) {
          if (k - o >= 0 && k - o <= 10) {
            aAB0[o] = __hfma2(gh8[k - o], h2_of(ab.x), aAB0[o]);
            aAB1[o] = __hfma2(gh8[k - o], h2_of(ab.y), aAB1[o]);
            aPM0[o] = __hfma2(gh8[k - o], h2_of(pm.x), aPM0[o]);
            aPM1[o] = __hfma2(gh8[k - o], h2_of(pm.y), aPM1[o]);
          }
        }
      }
#pragma unroll
      for (int o = 0; o < 2; ++o) {
        uint32_t uab0 = u_of(aAB0[o]), uab1 = u_of(aAB1[o]);
        uint32_t upm0 = u_of(aPM0[o]), upm1 = u_of(aPM1[o]);
        __half2 M1 = h2_of(__builtin_amdgcn_perm(uab1, uab0, 0x05040100));
        __half2 M2 = h2_of(__builtin_amdgcn_perm(uab1, uab0, 0x07060302));
        __half2 QP = h2_of(__builtin_amdgcn_perm(upm1, upm0, 0x05040100));
        __half2 QM = h2_of(__builtin_amdgcn_perm(upm1, upm0, 0x07060302));
        __half2 m12 = __hmul2(M1, M2);
        __half2 s1q = __hmul2(M1, M1);
        __half2 s2q = __hmul2(M2, M2);
        __half2 sumsq = __hmul2(__hadd2(QP, QM), kQS);
        __half2 eab = __hmul2(__hsub2(QP, QM), kQD);
        __half2 sg12 = __hsub2(eab, m12);
        __half2 sgsum = __hsub2(__hsub2(sumsq, s1q), s2q);
        __half2 num = __hmul2(__hfma2(m12, htwo, C1s), __hfma2(sg12, htwo, C2s));
        __half2 den = __hmul2(__hadd2(__hadd2(s1q, s2q), C1s),
                              __hadd2(sgsum, C2s));
        float ra = __low2float(num) * __builtin_amdgcn_rcpf(__low2float(den));
        float rb = __high2float(num) * __builtin_amdgcn_rcpf(__high2float(den));
        if (!__builtin_isfinite(ra)) ra = 0.f;
        if (!__builtin_isfinite(rb)) rb = 0.f;
        ssum += ra + rb;
      }
    }
  };

  // ---- pipeline ----
  prepass_chunk(tid);          // own round-1 chunk (vmcnt already waited)
  lds_barrier();
  // Phase A
  if (wid < 5) {
    asm volatile("s_waitcnt vmcnt(0)" ::: "memory");  // own r2 retired
    __builtin_amdgcn_sched_barrier(0);
    if (tid < 302) prepass_chunk(512 + tid);
  } else {
    stage2(0, 46, 320, 192);   // h rows 0..45 (184 tasks / 192)
  }
  lds_barrier();
  // Phase B
  if (wid < 5) {
    stage3(0, 18, 0, 320);     // out rows 0..35 (288 tasks / 320)
  } else {
    stage2(46, 28, 320, 192);  // h rows 46..73 (112 tasks / 192)
  }
  lds_barrier();
  // Phase C
  stage3(36, 14, 0, NT);       // out rows 36..63 (224 tasks / 512)

  // ---- block reduction (deterministic) ----
#pragma unroll
  for (int off = 32; off > 0; off >>= 1) ssum += __shfl_down(ssum, off, 64);
  if ((tid & 63) == 0) sWave[tid >> 6] = ssum;
  __syncthreads();
  if (tid == 0) {
    float t = 0.f;
#pragma unroll
    for (int w = 0; w < 8; ++w) t += sWave[w];
    partial[wgid] = t;
    __threadfence();                       // release: partial visible
    unsigned int ticket = atomicAdd(counter, 1u);   // device scope
    sLast = (ticket == NBLOCKS - 1);
  }
  __syncthreads();

  // ---- fused final reduce: last block, fixed order (deterministic) ----
  if (sLast) {
    __threadfence();                       // acquire: see all partials
    float s = 0.f;
    for (int i = tid; i < NBLOCKS; i += NT) s += partial[i];
#pragma unroll
    for (int off = 32; off > 0; off >>= 1) s += __shfl_down(s, off, 64);
    if ((tid & 63) == 0) sWave[tid >> 6] = s;
    __syncthreads();
    if (tid == 0) {
      float tot = 0.f;
#pragma unroll
      for (int w = 0; w < 8; ++w) tot += sWave[w];
      // mean((1 - ssim)/2) = 0.5 * (1 - mean(ssim))
      float val = 0.5f * (1.0f - tot * (1.0f / (32.0f * 512.0f * 512.0f)));
      if (!__builtin_isfinite(val)) val = 0.0f;
      out[0] = val;
    }
  }
}

extern "C" void kernel_launch(void* const* d_in, const int* in_sizes, int n_in,
                              void* d_out, int out_size, void* d_ws,
                              size_t ws_size, hipStream_t stream) {
  const float* img1 = (const float*)d_in[0];
  const float* img2 = (const float*)d_in[1];
  float* partial = (float*)d_ws;                       // 4096 floats
  unsigned int* counter = (unsigned int*)(partial + NBLOCKS);
  float* out = (float*)d_out;

  hipMemsetAsync(counter, 0, sizeof(unsigned int), stream);  // graph-legal
  hipLaunchKernelGGL(ssim_main, dim3(NBLOCKS), dim3(NT), 0, stream, img1,
                     img2, partial, counter, out);
}

// Round 20
// 35.365 us; speedup vs baseline: 3.9840x; 3.9840x over previous
//
#include <hip/hip_runtime.h>
#include <hip/hip_fp16.h>

// SSIM loss, fused separable 11x11 Gaussian conv + SSIM map + mean.
// Images: 32 x 1 x 512 x 512 fp32. Output: 1 fp32 scalar.
//
// R20 = R18 verbatim (best: 38.9 us) + float4-vectorized reduce kernel.
// R19's fused last-block reduction REVERTED: per-block __threadfence()
// on gfx950 forces cross-XCD L2 writeback per block (4096x) -> 3.6x
// regression. The tiny dependent reduce kernel is the cheap path.
//
// R18 structure: wave-role specialization
//   DMA r1: all threads chunk=tid. r2: waves 0-4 ch=512+tid (pad-safe).
//   per-wave counted waits: w0-4 vmcnt(2), w5-7 vmcnt(0); no barrier
//   before prepass-low. Phase A: w5-7 stage2-low || w0-4 prepass-high.
//   Phase B: w5-7 stage2-high || w0-4 stage3 rows 0..35. Phase C: all
//   stage3 rows 36..63. Packed-fp16 conv + pk epilogue (1/8 scale fold),
//   async global_load_lds, prepass pack + LDS aliasing, XCD swizzle.
//
// Alias map (HSTR=36, NPIXA=3328 incl pad): h rows 0..45 = dwords<1656 =
// chunks<414 (dead after prepass-low). h rows 46..73 = dwords 1656..2663
// (dead after prepass-high). prepass-high touches dwords 2048+ only.
// PAD dwords 3256..3327 never aliased.

#define IMGW 512
#define IMGH 512
#define NIMG 32
#define TW 32
#define TH 64
#define IN_H 74        // TH + 10
#define IN_W 44        // sPK row stride (dwords); cols 0..41 used
#define HSTR 36        // h row stride (dwords)
#define NPIX (IN_H * IN_W)     // 3256
#define NPIXA 3328     // raw region incl 18-chunk DMA overflow pad
#define NCHUNK (IN_H * 11)     // 814 16B chunks per image tile
#define NBX 16
#define NBY 8
#define NBLOCKS (NBX * NBY * NIMG)   // 4096
#define NT 512

typedef __attribute__((address_space(1))) const uint32_t ga_u32;
typedef __attribute__((address_space(3))) uint32_t ls_u32;

__device__ __forceinline__ void load16_lds(const float* g, float* l) {
  __builtin_amdgcn_global_load_lds((ga_u32*)g, (ls_u32*)l, 16, 0, 0);
}
__device__ __forceinline__ __half2 h2_of(uint32_t w) {
  return __builtin_bit_cast(__half2, w);
}
__device__ __forceinline__ uint32_t u_of(__half2 h) {
  return __builtin_bit_cast(uint32_t, h);
}
__device__ __forceinline__ void lds_barrier() {
  asm volatile("s_waitcnt lgkmcnt(0)" ::: "memory");
  __builtin_amdgcn_s_barrier();
  __builtin_amdgcn_sched_barrier(0);
}

__global__ __launch_bounds__(NT, 8) void ssim_main(
    const float* __restrict__ img1, const float* __restrict__ img2,
    float* __restrict__ partial) {
  __shared__ uint32_t uRaw[NPIXA * 2];  // raw A | raw B (each w/ pad)
  __shared__ uint32_t sPK[NPIX];        // packed (a,b) half2
  __shared__ float sWave[8];
  float* sA = (float*)uRaw;
  float* sB = (float*)(uRaw + NPIXA);
  uint32_t* hAB = uRaw;                 // [74][HSTR] aliases raw-A
  uint32_t* hPM = uRaw + NPIXA;         // [74][HSTR] aliases raw-B

  // Unnormalized Gaussian, 2*sigma^2 = 4 (faithful to reference).
  constexpr float g[11] = {0.0019304541f, 0.018315639f, 0.10539922f,
                           0.36787944f,   0.7788008f,   1.0f,
                           0.7788008f,    0.36787944f,  0.10539922f,
                           0.018315639f,  0.0019304541f};

  __half2 gh[11], gh8[11];
#pragma unroll
  for (int k = 0; k < 11; ++k) {
    gh[k] = __float2half2_rn(g[k]);
    gh8[k] = __float2half2_rn(g[k] * 0.125f);   // stage-3 scale fold
  }
  const __half2 c1m1 = __floats2half2_rn(1.0f, -1.0f);
  const __half2 kQS = __float2half2_rn(0.0625f);
  const __half2 kQD = __float2half2_rn(0.03125f);
  const __half2 C1s = __float2half2_rn(6.5025f / 64.0f);
  const __half2 C2s = __float2half2_rn(58.5225f / 64.0f);
  const __half2 htwo = __float2half2_rn(2.0f);

  const int tid = threadIdx.x;
  const int wid = tid >> 6;
  // XCD-chunked swizzle: each of 8 XCDs gets 512 consecutive tiles.
  const int bid = blockIdx.x;
  const int wgid = (bid & 7) * (NBLOCKS / 8) + (bid >> 3);
  const int img = wgid >> 7;
  const int by = (wgid >> 4) & 7;
  const int bx = wgid & 15;
  const int x0 = bx * TW - 5;
  const int y0 = by * TH - 5;
  const float* __restrict__ p1 = img1 + (size_t)img * (IMGW * IMGH);
  const float* __restrict__ p2 = img2 + (size_t)img * (IMGW * IMGH);
  const bool borderBlk =
      (bx == 0) || (bx == NBX - 1) || (by == 0) || (by == NBY - 1);

  auto src_of = [&](int ch) {
    int r = ch / 11;
    int cg = ch - r * 11;
    int gy = y0 + r;
    int gx = x0 + 4 * cg;
    int gyc = min(max(gy, 0), IMGH - 1);
    int gxc = min(max(gx, 0), IMGW - 4);
    return gyc * IMGW + gxc;
  };

  // ---- Stage 0: DMA. r1: all (own chunk). r2: waves 0-4 contiguous. ----
  {
    int src = src_of(tid);
    load16_lds(p1 + src, &sA[tid * 4]);
    load16_lds(p2 + src, &sB[tid * 4]);
  }
  if (wid < 5) {
    int ch = 512 + tid;                  // 512..831 (814+ -> pad dst)
    int src = src_of(min(ch, NCHUNK - 1));
    load16_lds(p1 + src, &sA[ch * 4]);
    load16_lds(p2 + src, &sB[ch * 4]);
    asm volatile("s_waitcnt vmcnt(2)" ::: "memory");  // r1 retired
  } else {
    asm volatile("s_waitcnt vmcnt(0)" ::: "memory");  // r1 retired
  }
  __builtin_amdgcn_sched_barrier(0);

  // ---- prepass worker: pack one chunk (a,b)->half2 into sPK ----
  auto prepass_chunk = [&](int ch) {
    float4 a = *(const float4*)&sA[ch * 4];
    float4 b = *(const float4*)&sB[ch * 4];
    uint4 w;
    if (!borderBlk) {
      w.x = u_of(__floats2half2_rn(a.x, b.x));
      w.y = u_of(__floats2half2_rn(a.y, b.y));
      w.z = u_of(__floats2half2_rn(a.z, b.z));
      w.w = u_of(__floats2half2_rn(a.w, b.w));
    } else {
      int r = ch / 11;
      int cg = ch - r * 11;
      int gy = y0 + r;
      int gx = x0 + 4 * cg;
      bool rowok = (gy >= 0) && (gy < IMGH);
      float av[4] = {a.x, a.y, a.z, a.w};
      float bv[4] = {b.x, b.y, b.z, b.w};
      uint32_t* wp = (uint32_t*)&w;
#pragma unroll
      for (int j = 0; j < 4; ++j) {
        bool ok = rowok && (gx + j >= 0) && (gx + j < IMGW);
        wp[j] = u_of(__floats2half2_rn(ok ? av[j] : 0.f, ok ? bv[j] : 0.f));
      }
    }
    *(uint4*)&sPK[ch * 4] = w;
  };

  // ---- stage2 worker: 8-wide tasks over thread range [tbase,tbase+tcnt) ----
  auto stage2 = [&](int rowbase, int nrows, int tbase, int tcnt) {
    for (int idx = tid - tbase; idx < nrows * 4; idx += tcnt) {
      int r = rowbase + (idx >> 2);
      int c0 = (idx & 3) << 3;
      int base = r * IN_W + c0;
      __half2 ab[18], pm2[18];
      {
        uint4 w0 = *(const uint4*)&sPK[base];
        uint4 w1 = *(const uint4*)&sPK[base + 4];
        uint4 w2 = *(const uint4*)&sPK[base + 8];
        uint4 w3 = *(const uint4*)&sPK[base + 12];
        uint2 w4 = *(const uint2*)&sPK[base + 16];
        uint32_t ws[18] = {w0.x, w0.y, w0.z, w0.w, w1.x, w1.y, w1.z, w1.w,
                           w2.x, w2.y, w2.z, w2.w, w3.x, w3.y, w3.z, w3.w,
                           w4.x, w4.y};
#pragma unroll
        for (int k = 0; k < 18; ++k) {
          __half2 w = h2_of(ws[k]);
          ab[k] = w;
          __half2 t = __hfma2(__lowhigh2highlow(w), c1m1, w);  // (p, -m)
          pm2[k] = __hmul2(t, t);                              // (p2, m2)
        }
      }
      uint32_t oab[8], opm[8];
#pragma unroll
      for (int o = 0; o < 8; ++o) {
        __half2 cab = __float2half2_rn(0.0f);
        __half2 cpm = __float2half2_rn(0.0f);
#pragma unroll
        for (int k = 0; k < 11; ++k) {
          cab = __hfma2(gh[k], ab[o + k], cab);
          cpm = __hfma2(gh[k], pm2[o + k], cpm);
        }
        oab[o] = u_of(cab);
        opm[o] = u_of(cpm);
      }
      int hb = r * HSTR + c0;
      *(uint4*)&hAB[hb] = make_uint4(oab[0], oab[1], oab[2], oab[3]);
      *(uint4*)&hAB[hb + 4] = make_uint4(oab[4], oab[5], oab[6], oab[7]);
      *(uint4*)&hPM[hb] = make_uint4(opm[0], opm[1], opm[2], opm[3]);
      *(uint4*)&hPM[hb + 4] = make_uint4(opm[4], opm[5], opm[6], opm[7]);
    }
  };

  float ssum = 0.f;
  // ---- stage3 worker: 2-row x 2-col groups, rows r0base..+2*ngroups ----
  auto stage3 = [&](int r0base, int ngroups, int tbase, int tcnt) {
    for (int t = tid - tbase; t < ngroups * 16; t += tcnt) {
      int cp = t & 15;
      int r0 = r0base + ((t >> 4) << 1);
      __half2 aAB0[2], aAB1[2], aPM0[2], aPM1[2];
#pragma unroll
      for (int o = 0; o < 2; ++o) {
        aAB0[o] = __float2half2_rn(0.f);
        aAB1[o] = __float2half2_rn(0.f);
        aPM0[o] = __float2half2_rn(0.f);
        aPM1[o] = __float2half2_rn(0.f);
      }
#pragma unroll
      for (int k = 0; k < 12; ++k) {
        int row = r0 + k;
        uint2 ab = *(const uint2*)&hAB[row * HSTR + 2 * cp];
        uint2 pm = *(const uint2*)&hPM[row * HSTR + 2 * cp];
#pragma unroll
        for (int o = 0; o < 2; ++o) {
          if (k - o >= 0 && k - o <= 10) {
            aAB0[o] = __hfma2(gh8[k - o], h2_of(ab.x), aAB0[o]);
            aAB1[o] = __hfma2(gh8[k - o], h2_of(ab.y), aAB1[o]);
            aPM0[o] = __hfma2(gh8[k - o], h2_of(pm.x), aPM0[o]);
            aPM1[o] = __hfma2(gh8[k - o], h2_of(pm.y), aPM1[o]);
          }
        }
      }
#pragma unroll
      for (int o = 0; o < 2; ++o) {
        uint32_t uab0 = u_of(aAB0[o]), uab1 = u_of(aAB1[o]);
        uint32_t upm0 = u_of(aPM0[o]), upm1 = u_of(aPM1[o]);
        __half2 M1 = h2_of(__builtin_amdgcn_perm(uab1, uab0, 0x05040100));
        __half2 M2 = h2_of(__builtin_amdgcn_perm(uab1, uab0, 0x07060302));
        __half2 QP = h2_of(__builtin_amdgcn_perm(upm1, upm0, 0x05040100));
        __half2 QM = h2_of(__builtin_amdgcn_perm(upm1, upm0, 0x07060302));
        __half2 m12 = __hmul2(M1, M2);
        __half2 s1q = __hmul2(M1, M1);
        __half2 s2q = __hmul2(M2, M2);
        __half2 sumsq = __hmul2(__hadd2(QP, QM), kQS);
        __half2 eab = __hmul2(__hsub2(QP, QM), kQD);
        __half2 sg12 = __hsub2(eab, m12);
        __half2 sgsum = __hsub2(__hsub2(sumsq, s1q), s2q);
        __half2 num = __hmul2(__hfma2(m12, htwo, C1s), __hfma2(sg12, htwo, C2s));
        __half2 den = __hmul2(__hadd2(__hadd2(s1q, s2q), C1s),
                              __hadd2(sgsum, C2s));
        float ra = __low2float(num) * __builtin_amdgcn_rcpf(__low2float(den));
        float rb = __high2float(num) * __builtin_amdgcn_rcpf(__high2float(den));
        if (!__builtin_isfinite(ra)) ra = 0.f;
        if (!__builtin_isfinite(rb)) rb = 0.f;
        ssum += ra + rb;
      }
    }
  };

  // ---- pipeline ----
  prepass_chunk(tid);          // own round-1 chunk (vmcnt already waited)
  lds_barrier();
  // Phase A
  if (wid < 5) {
    asm volatile("s_waitcnt vmcnt(0)" ::: "memory");  // own r2 retired
    __builtin_amdgcn_sched_barrier(0);
    if (tid < 302) prepass_chunk(512 + tid);
  } else {
    stage2(0, 46, 320, 192);   // h rows 0..45 (184 tasks / 192)
  }
  lds_barrier();
  // Phase B
  if (wid < 5) {
    stage3(0, 18, 0, 320);     // out rows 0..35 (288 tasks / 320)
  } else {
    stage2(46, 28, 320, 192);  // h rows 46..73 (112 tasks / 192)
  }
  lds_barrier();
  // Phase C
  stage3(36, 14, 0, NT);       // out rows 36..63 (224 tasks / 512)

  // ---- block reduction (deterministic) ----
#pragma unroll
  for (int off = 32; off > 0; off >>= 1) ssum += __shfl_down(ssum, off, 64);
  if ((tid & 63) == 0) sWave[tid >> 6] = ssum;
  __syncthreads();
  if (tid == 0) {
    float t = 0.f;
#pragma unroll
    for (int w = 0; w < 8; ++w) t += sWave[w];
    partial[wgid] = t;
  }
}

__global__ __launch_bounds__(256) void ssim_reduce(
    const float* __restrict__ partial, float* __restrict__ out) {
  const int tid = threadIdx.x;
  // 4096 floats = 1024 float4; 256 threads x 4 vector loads each.
  const float4* p4 = (const float4*)partial;
  float s = 0.f;
#pragma unroll
  for (int i = 0; i < 4; ++i) {
    float4 v = p4[tid + 256 * i];
    s += (v.x + v.y) + (v.z + v.w);
  }
#pragma unroll
  for (int off = 32; off > 0; off >>= 1) s += __shfl_down(s, off, 64);
  __shared__ float sw[4];
  if ((tid & 63) == 0) sw[tid >> 6] = s;
  __syncthreads();
  if (tid == 0) {
    float tot = sw[0] + sw[1] + sw[2] + sw[3];
    // mean((1 - ssim)/2) = 0.5 * (1 - mean(ssim))
    float val = 0.5f * (1.0f - tot * (1.0f / (32.0f * 512.0f * 512.0f)));
    if (!__builtin_isfinite(val)) val = 0.0f;
    out[0] = val;
  }
}

extern "C" void kernel_launch(void* const* d_in, const int* in_sizes, int n_in,
                              void* d_out, int out_size, void* d_ws,
                              size_t ws_size, hipStream_t stream) {
  const float* img1 = (const float*)d_in[0];
  const float* img2 = (const float*)d_in[1];
  float* partial = (float*)d_ws;  // 4096 floats = 16 KB
  float* out = (float*)d_out;

  hipLaunchKernelGGL(ssim_main, dim3(NBLOCKS), dim3(NT), 0, stream, img1,
                     img2, partial);
  hipLaunchKernelGGL(ssim_reduce, dim3(1), dim3(256), 0, stream, partial, out);
}